// Round 11
// baseline (63.225 us; speedup 1.0000x reference)
//
#include <hip/hip_runtime.h>
#include <stdint.h>

#define B_  16
#define H_  512
#define W_  512
#define HW_ (H_*W_)
#define N_  (B_*HW_)

#define TX 32
#define TY 16
#define NBLK 8192   // (512/32)*(512/16)*16

// plane geometry (flat-indexed)
#define GYr 26
#define GXc 48     // gray: rows ty0-5.., cols tx0-8..  (12 quads)
#define TWYr 26
#define TWXc 40    // t: rows ty0-5.., cols tx0-3.. (10 quads; cols 0..37 meaningful)
#define BLYr 22
#define BLXc 40    // blur: rows ty0-3.., cols tx0-3..
#define MGYr 20
#define MGXc 36    // mag/soff: rows ty0-2.., cols tx0-2.. (9 quads)
#define EYr 18
#define EXc 34     // e: rows ty0-1.., cols tx0-1..

#define G0 0.054488685f
#define G1 0.244201342f
#define G2 0.402619947f

__device__ __forceinline__ int reflect512(int i) {
    i = i < 0 ? -i : i;
    return i > 511 ? 1022 - i : i;
}
__device__ __forceinline__ int clamp511(int v) {
    return v < 0 ? 0 : (v > 511 ? 511 : v);
}

__global__ __launch_bounds__(128)
void k_canny(const float* __restrict__ pred, const float* __restrict__ sketch,
             const float* __restrict__ matte, float* __restrict__ partials) {
    // g / blur / e pairwise non-overlapping in time
    __shared__ __align__(16) union {
        float g[GYr*GXc];       // 4992 B
        float blur[BLYr*BLXc];  // 3520 B
        int   e[EYr*EXc];       // 2448 B
    } uA;
    __shared__ __align__(16) union {
        float t[TWYr*TWXc];     // 4160 B
        float mag[MGYr*MGXc];   // 2880 B
    } uT;
    __shared__ __align__(8) int16_t sOff[MGYr*MGXc];
    __shared__ float wsum[2];

    const int tid = threadIdx.x;
    const int tx0 = blockIdx.x * TX;
    const int ty0 = blockIdx.y * TY;
    const int b   = blockIdx.z;
    const bool interior = (blockIdx.x >= 1) & (blockIdx.x <= 14) &
                          (blockIdx.y >= 1) & (blockIdx.y <= 30);

    const float* pb = pred   + (size_t)b * 3 * HW_;
    const float* mb = matte  + (size_t)b * HW_;
    const float* sb = sketch + (size_t)b * HW_;

    // ---- A: gray = mean3(pred)*matte, reflect-staged, 26x48 ----
    {
        const bool xfast = (tx0 >= 8) && (tx0 + 39 + 8 < W_);
        for (int u = tid; u < GYr*12; u += 128) {
            int r = u / 12, q = u - r*12;
            int ys = reflect512(ty0 - 5 + r);
            int gx = tx0 - 8 + q*4;
            float4 res;
            if (xfast) {
                const float* prow = pb + ys*W_ + gx;
                float4 p0 = *(const float4*)(prow);
                float4 p1 = *(const float4*)(prow + HW_);
                float4 p2 = *(const float4*)(prow + 2*HW_);
                float4 m4 = *(const float4*)(mb + ys*W_ + gx);
                res.x = (p0.x+p1.x+p2.x)*m4.x*(1.f/3.f);
                res.y = (p0.y+p1.y+p2.y)*m4.y*(1.f/3.f);
                res.z = (p0.z+p1.z+p2.z)*m4.z*(1.f/3.f);
                res.w = (p0.w+p1.w+p2.w)*m4.w*(1.f/3.f);
            } else {
                float tmp[4];
                #pragma unroll
                for (int e2 = 0; e2 < 4; ++e2) {
                    int xs = reflect512(gx + e2);
                    int o  = ys*W_ + xs;
                    tmp[e2] = (pb[o] + pb[o+HW_] + pb[o+2*HW_]) * mb[o] * (1.f/3.f);
                }
                res.x = tmp[0]; res.y = tmp[1]; res.z = tmp[2]; res.w = tmp[3];
            }
            *(float4*)&uA.g[4*u] = res;   // r*48 + q*4 == 4u
        }
    }
    __syncthreads();

    // ---- B1: horizontal gaussian -> t ----
    if (interior) {
        for (int u = tid; u < 260; u += 128) {     // 26 rows x 10 quads
            int r = u / 10, k = u - (u / 10) * 10;
            const float* gq = &uA.g[r*GXc + 4*k];
            float4 q0 = *(const float4*)(gq);
            float4 q1 = *(const float4*)(gq + 4);
            float4 q2 = *(const float4*)(gq + 8);
            float4 o;
            o.x = G0*(q0.w + q1.w) + G1*(q1.x + q1.z) + G2*q1.y;
            o.y = G0*(q1.x + q2.x) + G1*(q1.y + q1.w) + G2*q1.z;
            o.z = G0*(q1.y + q2.y) + G1*(q1.z + q2.x) + G2*q1.w;
            o.w = G0*(q1.z + q2.z) + G1*(q1.w + q2.y) + G2*q2.x;
            *(float4*)&uT.t[r*TWXc + 4*k] = o;
        }
    } else {
        for (int u = tid; u < 26*38; u += 128) {   // 26 rows x 38 cols
            int r = u / 38, c = u - (u / 38) * 38;
            int xc = clamp511(tx0 - 3 + c) - (tx0 - 8);
            int gi = r*GXc + xc;
            uT.t[r*TWXc + c] =
                G0*(uA.g[gi-2] + uA.g[gi+2])
              + G1*(uA.g[gi-1] + uA.g[gi+1])
              + G2*uA.g[gi];
        }
    }
    __syncthreads();

    // ---- B2: vertical gaussian -> blur ----
    if (interior) {
        for (int u = tid; u < 220; u += 128) {     // 22 rows x 10 quads
            int r = u / 10, k = u - (u / 10) * 10;
            const float* tq = &uT.t[r*TWXc + 4*k];
            float4 a = *(const float4*)(tq);
            float4 bq = *(const float4*)(tq + TWXc);
            float4 c = *(const float4*)(tq + 2*TWXc);
            float4 d = *(const float4*)(tq + 3*TWXc);
            float4 e = *(const float4*)(tq + 4*TWXc);
            float4 o;
            o.x = G0*(a.x+e.x) + G1*(bq.x+d.x) + G2*c.x;
            o.y = G0*(a.y+e.y) + G1*(bq.y+d.y) + G2*c.y;
            o.z = G0*(a.z+e.z) + G1*(bq.z+d.z) + G2*c.z;
            o.w = G0*(a.w+e.w) + G1*(bq.w+d.w) + G2*c.w;
            *(float4*)&uA.blur[r*BLXc + 4*k] = o;
        }
    } else {
        for (int u = tid; u < 22*38; u += 128) {   // 22 rows x 38 cols
            int r = u / 38, c = u - (u / 38) * 38;
            int yc = clamp511(ty0 - 3 + r) - (ty0 - 5);   // [2,23]
            int ti = (yc-2)*TWXc + c;
            uA.blur[r*BLXc + c] =
                G0*(uT.t[ti] + uT.t[ti+4*TWXc])
              + G1*(uT.t[ti+TWXc] + uT.t[ti+3*TWXc])
              + G2*uT.t[ti+2*TWXc];
        }
    }
    __syncthreads();

    // ---- C: sobel -> mag2 + NMS offset ----
    if (interior) {
        for (int u = tid; u < 180; u += 128) {     // 20 rows x 9 quads
            int r = u / 9, k = u - (u / 9) * 9;
            const float* b0 = &uA.blur[r*BLXc + 4*k];
            float4 a0 = *(const float4*)(b0);
            float4 a1 = *(const float4*)(b0 + 4);
            float4 bq0 = *(const float4*)(b0 + BLXc);
            float4 bq1 = *(const float4*)(b0 + BLXc + 4);
            float4 c0 = *(const float4*)(b0 + 2*BLXc);
            float4 c1 = *(const float4*)(b0 + 2*BLXc + 4);
            float wa[6] = {a0.x,a0.y,a0.z,a0.w, a1.x,a1.y};
            float wb[6] = {bq0.x,bq0.y,bq0.z,bq0.w, bq1.x,bq1.y};
            float wc[6] = {c0.x,c0.y,c0.z,c0.w, c1.x,c1.y};
            float cs[6], rd[6];
            #pragma unroll
            for (int i = 0; i < 6; ++i) {
                cs[i] = wa[i] + 2.f*wb[i] + wc[i];
                rd[i] = wc[i] - wa[i];
            }
            float4 m2v; int ov[4];
            #pragma unroll
            for (int e2 = 0; e2 < 4; ++e2) {
                float gxv = cs[e2+2] - cs[e2];
                float gyv = rd[e2] + 2.f*rd[e2+1] + rd[e2+2];
                ((float*)&m2v)[e2] = fmaf(gxv*gxv + gyv*gyv, 0.015625f, 1e-6f);
                float agx = fabsf(gxv), agy = fabsf(gyv);
                int off;
                if      (agy <= 0.41421356f * agx) off = (gxv >= 0.f) ? 1 : -1;
                else if (agy >= 2.41421356f * agx) off = (gyv >  0.f) ? -MGXc : MGXc;
                else off = ((gyv > 0.f) ? -MGXc : MGXc) + ((gxv > 0.f) ? 1 : -1);
                ov[e2] = off;
            }
            int mi = r*MGXc + 4*k;
            *(float4*)&uT.mag[mi] = m2v;
            uint2 ow;
            ow.x = (uint32_t)(uint16_t)(int16_t)ov[0] | ((uint32_t)(uint16_t)(int16_t)ov[1] << 16);
            ow.y = (uint32_t)(uint16_t)(int16_t)ov[2] | ((uint32_t)(uint16_t)(int16_t)ov[3] << 16);
            *(uint2*)&sOff[mi] = ow;
        }
    } else {
        for (int u = tid; u < MGYr*MGXc; u += 128) {
            int r = u / MGXc, c = u - (u / MGXc) * MGXc;
            int y = ty0 - 2 + r, x = tx0 - 2 + c;
            float m2 = 0.f; int off = 0;
            if ((unsigned)y < 512u && (unsigned)x < 512u) {
                int r0 = clamp511(y-1) - (ty0-3);
                int r1 = y - (ty0-3);
                int r2 = clamp511(y+1) - (ty0-3);
                int cm = clamp511(x-1) - (tx0-3);
                int cc = x - (tx0-3);
                int cp = clamp511(x+1) - (tx0-3);
                float a00 = uA.blur[r0*BLXc+cm], a01 = uA.blur[r0*BLXc+cc], a02 = uA.blur[r0*BLXc+cp];
                float a10 = uA.blur[r1*BLXc+cm],                            a12 = uA.blur[r1*BLXc+cp];
                float a20 = uA.blur[r2*BLXc+cm], a21 = uA.blur[r2*BLXc+cc], a22 = uA.blur[r2*BLXc+cp];
                float gxv = (a02 + 2.f*a12 + a22) - (a00 + 2.f*a10 + a20);
                float gyv = (a20 + 2.f*a21 + a22) - (a00 + 2.f*a01 + a02);
                m2 = fmaf(gxv*gxv + gyv*gyv, 0.015625f, 1e-6f);
                float agx = fabsf(gxv), agy = fabsf(gyv);
                if      (agy <= 0.41421356f * agx) off = (gxv >= 0.f) ? 1 : -1;
                else if (agy >= 2.41421356f * agx) off = (gyv >  0.f) ? -MGXc : MGXc;
                else off = ((gyv > 0.f) ? -MGXc : MGXc) + ((gxv > 0.f) ? 1 : -1);
            }
            uT.mag[r*MGXc + c] = m2;
            sOff[r*MGXc + c] = (int16_t)off;
        }
    }
    __syncthreads();

    // ---- D: NMS + double threshold -> class [18][34] ----
    {
        int r = tid / EXc, c = tid - (tid / EXc) * EXc;
        #pragma unroll
        for (int it = 0; it < 5; ++it) {
            if (r < EYr) {
                int mi = r*MGXc + c + MGXc + 1;     // center
                float m2 = uT.mag[mi];
                int off = (int)sOff[mi];
                float n1 = uT.mag[mi + off];
                float n2 = uT.mag[mi - off];
                int cls = 0;
                if (m2 > n1 && m2 > n2) cls = (m2 > 0.01f) + (m2 > 0.04f);
                uA.e[r*EXc + c] = cls;
            }
            c += 26; r += 3; if (c >= EXc) { c -= EXc; ++r; }   // +128 over stride 34
        }
    }
    __syncthreads();

    // ---- E: guarded 1-sweep hysteresis + MSE, exactly 1 quad/thread ----
    {
        float lacc = 0.f;
        int r = tid >> 3, q8 = tid & 7;
        int gy = ty0 + r, gx = tx0 + q8*4;
        int ei = (r+1)*EXc + q8*4 + 1;
        int cls[4];
        #pragma unroll
        for (int j = 0; j < 4; ++j) cls[j] = uA.e[ei+j];
        if (cls[0] == 1 || cls[1] == 1 || cls[2] == 1 || cls[3] == 1) {
            #pragma unroll
            for (int j = 0; j < 4; ++j) {
                if (cls[j] == 1) {
                    int cc = ei + j;
                    bool pr = (uA.e[cc-EXc-1] == 2) | (uA.e[cc-EXc] == 2) | (uA.e[cc-EXc+1] == 2)
                            | (uA.e[cc-1]     == 2) |                       (uA.e[cc+1]     == 2)
                            | (uA.e[cc+EXc-1] == 2) | (uA.e[cc+EXc] == 2) | (uA.e[cc+EXc+1] == 2);
                    if (pr) cls[j] = 2;
                }
            }
        }
        float4 s4 = *(const float4*)(sb + gy*W_ + gx);
        float4 m4 = *(const float4*)(mb + gy*W_ + gx);
        float tt, d;
        tt = fminf(fmaxf(s4.x*m4.x, 0.f), 1.f); d = 0.5f*(float)cls[0] - tt; lacc += d*d;
        tt = fminf(fmaxf(s4.y*m4.y, 0.f), 1.f); d = 0.5f*(float)cls[1] - tt; lacc += d*d;
        tt = fminf(fmaxf(s4.z*m4.z, 0.f), 1.f); d = 0.5f*(float)cls[2] - tt; lacc += d*d;
        tt = fminf(fmaxf(s4.w*m4.w, 0.f), 1.f); d = 0.5f*(float)cls[3] - tt; lacc += d*d;

        #pragma unroll
        for (int off = 32; off > 0; off >>= 1)
            lacc += __shfl_down(lacc, off, 64);
        if ((tid & 63) == 0) wsum[tid >> 6] = lacc;
    }
    __syncthreads();
    if (tid == 0) {
        int bid = (blockIdx.z * gridDim.y + blockIdx.y) * gridDim.x + blockIdx.x;
        partials[bid] = wsum[0] + wsum[1];
    }
}

__global__ __launch_bounds__(256)
void k_final(const float* __restrict__ partials, float* __restrict__ out) {
    int tid = threadIdx.x;
    float acc = 0.f;
    #pragma unroll
    for (int j = 0; j < NBLK/256; ++j) acc += partials[j*256 + tid];
    #pragma unroll
    for (int off = 32; off > 0; off >>= 1)
        acc += __shfl_down(acc, off, 64);
    __shared__ float ws[4];
    if ((tid & 63) == 0) ws[tid >> 6] = acc;
    __syncthreads();
    if (tid == 0) out[0] = (ws[0] + ws[1] + ws[2] + ws[3]) * (1.0f / (float)N_);
}

extern "C" void kernel_launch(void* const* d_in, const int* in_sizes, int n_in,
                              void* d_out, int out_size, void* d_ws, size_t ws_size,
                              hipStream_t stream) {
    const float* pred   = (const float*)d_in[0];
    const float* sketch = (const float*)d_in[1];
    const float* matte  = (const float*)d_in[2];
    float* out = (float*)d_out;
    float* partials = (float*)d_ws;   // NBLK floats

    dim3 blk(128);
    dim3 grd(W_/TX, H_/TY, B_);   // (16, 32, 16) = 8192 blocks
    k_canny<<<grd, blk, 0, stream>>>(pred, sketch, matte, partials);
    k_final<<<1, dim3(256), 0, stream>>>(partials, out);
}

// Round 12
// 50.880 us; speedup vs baseline: 1.2426x; 1.2426x over previous
//
#include <hip/hip_runtime.h>
#include <stdint.h>

#define B_  16
#define H_  512
#define W_  512
#define HW_ (H_*W_)
#define N_  (B_*HW_)

#define G0 0.054488685f
#define G1 0.244201342f
#define G2 0.402619947f

#define XT 10              // x tiles, 54 valid cols each (lane 5..58)
#define YT 16              // y tiles, 32 rows each
#define NWAVE (XT*YT*B_)   // 2560
#define NBLKC (NWAVE/4)    // 640 blocks x 4 independent waves

__device__ __forceinline__ int reflect512(int i) {
    i = i < 0 ? -i : i;
    return i > 511 ? 1022 - i : i;
}
__device__ __forceinline__ float shfl_f(float v, int abyte) {
    return __int_as_float(__builtin_amdgcn_ds_bpermute(abyte, __float_as_int(v)));
}
__device__ __forceinline__ int shfl_i(int v, int abyte) {
    return __builtin_amdgcn_ds_bpermute(abyte, v);
}

__global__ __launch_bounds__(256)
void k_canny(const float* __restrict__ pred, const float* __restrict__ sketch,
             const float* __restrict__ matte, float* __restrict__ partials)
{
    const int lane = threadIdx.x & 63;
    const int wid  = threadIdx.x >> 6;
    const int tile = blockIdx.x * 4 + wid;
    const int tx = tile % XT;
    const int t2 = tile / XT;
    const int ty = t2 & 15;
    const int b  = t2 >> 4;

    const int x  = tx*54 - 5 + lane;       // [-5, 544]
    const int xr = reflect512(x);
    const int y0 = ty*32;

    const float* p0 = pred + (size_t)b*3*HW_ + xr;
    const float* p1 = p0 + HW_;
    const float* p2 = p0 + 2*HW_;
    const float* mp = matte  + (size_t)b*HW_ + xr;
    const float* sp = sketch + (size_t)b*HW_ + xr;

    // bpermute byte addresses (pull from lane +/- k)
    const int am1 = ((lane-1)&63)<<2, ap1 = ((lane+1)&63)<<2;
    const int am2 = ((lane-2)&63)<<2, ap2 = ((lane+2)&63)<<2;

    const bool xin  = (x >= 0) & (x < 512);
    const bool xgt0 = (x > 0), xlt511 = (x < 511);
    const bool lv   = (lane >= 5) & (lane <= 58) & (x < 512);

    // register FIFOs (software pipeline, depth 15)
    float g_prev = 0.f;                       // gray row (prev step)
    float t0=0,t1=0,t2f=0,t3=0,t4=0;          // h-blur rows
    float bf0=0,bf1=0,bf2=0;                  // blur rows
    float mf0=0,mf1=0,mf2=0;                  // mag^2 rows
    int   ox0=0,oy0=0,ox1=0,oy1=0;            // NMS offsets (2-deep)
    int   e0=0,e1=0,e2=0;                     // class rows
    float skA=0,mtA=0,skB=0,mtB=0;            // loss operands (2-deep)
    float lacc = 0.f;

    for (int s = 0; s < 47; ++s) {
        // 1) gray load, row yL = y0-5+s (reflected), only rows that are needed
        float vg = 0.f;
        if (s <= 41) {
            int o = reflect512(y0 - 5 + s) * W_;
            vg = (p0[o] + p1[o] + p2[o]) * mp[o] * (1.f/3.f);
        }
        // loss prefetch for row yH(s+2) = y0-13+s
        float nsk = 0.f, nmt = 0.f;
        {
            int yS = y0 - 13 + s;
            if (yS >= y0 && yS < y0 + 32) { int o = yS*W_; nsk = sp[o]; nmt = mp[o]; }
        }
        // 2) horizontal gaussian for row y0-6+s (from g_prev, lane shuffles)
        float gm1 = shfl_f(g_prev, am1), gp1v = shfl_f(g_prev, ap1);
        float gm2 = shfl_f(g_prev, am2), gp2v = shfl_f(g_prev, ap2);
        float th = G0*(gm2+gp2v) + G1*(gm1+gp1v) + G2*g_prev;
        // 3) vertical gaussian for row y0-9+s (t-FIFO; reflect handled at load)
        float bl = G0*(t0+t4) + G1*(t1+t3) + G2*t2f;
        // 4) sobel -> mag^2 + NMS offset for row yM = y0-11+s
        int yM = y0 - 11 + s;
        float b0e = (yM > 0)   ? bf0 : bf1;      // y replicate
        float b2e = (yM < 511) ? bf2 : bf1;
        float cs  = b0e + 2.f*bf1 + b2e;         // column sum
        float rdv = b2e - b0e;                   // row diff
        float csm = shfl_f(cs, am1),  csp = shfl_f(cs, ap1);
        float rdm = shfl_f(rdv, am1), rdp = shfl_f(rdv, ap1);
        csm = xgt0 ? csm : cs;   csp = xlt511 ? csp : cs;    // x replicate
        rdm = xgt0 ? rdm : rdv;  rdp = xlt511 ? rdp : rdv;
        float gx = csp - csm;
        float gy = rdm + 2.f*rdv + rdp;
        float m2n = fmaf(gx*gx + gy*gy, 0.015625f, 1e-6f);
        bool iny = (yM >= 0) & (yM < 512);
        m2n = (iny & xin) ? m2n : 0.f;           // zero outside image (NMS pad)
        float agx = fabsf(gx), agy = fabsf(gy);
        int oxn, oyn;
        if      (agy <= 0.41421356f*agx) { oxn = (gx >= 0.f) ? 1 : -1; oyn = 0; }
        else if (agy >= 2.41421356f*agx) { oxn = 0; oyn = (gy > 0.f) ? -1 : 1; }
        else { oxn = (gx > 0.f) ? 1 : -1; oyn = (gy > 0.f) ? -1 : 1; }
        // 5) NMS + double threshold for row yE = y0-13+s (mag FIFO + delayed off)
        float m0m = shfl_f(mf0, am1), m0p = shfl_f(mf0, ap1);
        float m1m = shfl_f(mf1, am1), m1p = shfl_f(mf1, ap1);
        float m2m = shfl_f(mf2, am1), m2p = shfl_f(mf2, ap1);
        float r0v = (ox0 < 0) ? m0m : ((ox0 > 0) ? m0p : mf0);
        float r1v = (ox0 < 0) ? m1m : ((ox0 > 0) ? m1p : mf1);
        float r2v = (ox0 < 0) ? m2m : ((ox0 > 0) ? m2p : mf2);
        float n1  = (oy0 < 0) ? r0v : ((oy0 > 0) ? r2v : r1v);
        float r0w = (ox0 > 0) ? m0m : ((ox0 < 0) ? m0p : mf0);
        float r1w = (ox0 > 0) ? m1m : ((ox0 < 0) ? m1p : mf1);
        float r2w = (ox0 > 0) ? m2m : ((ox0 < 0) ? m2p : mf2);
        float n2  = (oy0 > 0) ? r0w : ((oy0 < 0) ? r2w : r1w);
        float mc = mf1;
        int cls = 0;
        if (mc > n1 && mc > n2) cls = (mc > 0.01f) + (mc > 0.04f);
        // 6) hysteresis + MSE for output row yH = y0-15+s
        if (s >= 15) {
            int e0m = shfl_i(e0, am1), e0p = shfl_i(e0, ap1);
            int e1m = shfl_i(e1, am1), e1p = shfl_i(e1, ap1);
            int e2m = shfl_i(e2, am1), e2p = shfl_i(e2, ap1);
            int orall = e0m|e0|e0p|e1m|e1p|e2m|e2|e2p;   // strong <=> bit1 set
            int fin = ((e1 == 1) && (orall & 2)) ? 2 : e1;
            float vf = 0.5f * (float)fin;
            float tt = fminf(fmaxf(skA*mtA, 0.f), 1.f);
            float d  = vf - tt;
            lacc += lv ? d*d : 0.f;
        }
        // FIFO shifts
        g_prev = vg;
        t0=t1; t1=t2f; t2f=t3; t3=t4; t4=th;
        bf0=bf1; bf1=bf2; bf2=bl;
        mf0=mf1; mf1=mf2; mf2=m2n;
        ox0=ox1; oy0=oy1; ox1=oxn; oy1=oyn;
        e0=e1; e1=e2; e2=cls;
        skA=skB; mtA=mtB; skB=nsk; mtB=nmt;
    }

    #pragma unroll
    for (int off = 32; off > 0; off >>= 1)
        lacc += __shfl_down(lacc, off, 64);
    if (lane == 0) partials[tile] = lacc;
}

__global__ __launch_bounds__(256)
void k_final(const float* __restrict__ partials, float* __restrict__ out) {
    int tid = threadIdx.x;
    float acc = 0.f;
    #pragma unroll
    for (int j = 0; j < NWAVE/256; ++j) acc += partials[j*256 + tid];
    #pragma unroll
    for (int off = 32; off > 0; off >>= 1)
        acc += __shfl_down(acc, off, 64);
    __shared__ float ws[4];
    if ((tid & 63) == 0) ws[tid >> 6] = acc;
    __syncthreads();
    if (tid == 0) out[0] = (ws[0] + ws[1] + ws[2] + ws[3]) * (1.0f / (float)N_);
}

extern "C" void kernel_launch(void* const* d_in, const int* in_sizes, int n_in,
                              void* d_out, int out_size, void* d_ws, size_t ws_size,
                              hipStream_t stream) {
    const float* pred   = (const float*)d_in[0];
    const float* sketch = (const float*)d_in[1];
    const float* matte  = (const float*)d_in[2];
    float* out = (float*)d_out;
    float* partials = (float*)d_ws;   // NWAVE floats

    k_canny<<<NBLKC, 256, 0, stream>>>(pred, sketch, matte, partials);
    k_final<<<1, 256, 0, stream>>>(partials, out);
}

// Round 13
// 43.618 us; speedup vs baseline: 1.4495x; 1.1665x over previous
//
#include <hip/hip_runtime.h>
#include <stdint.h>

#define B_  16
#define H_  512
#define W_  512
#define HW_ (H_*W_)
#define N_  (B_*HW_)

#define G0 0.054488685f
#define G1 0.244201342f
#define G2 0.402619947f

#define XT 10              // x tiles, 54 valid cols each (lane 5..58)
#define YT 32              // y tiles, 16 rows each
#define NWAVE (XT*YT*B_)   // 5120
#define NBLKC (NWAVE/4)    // 1280 blocks x 4 independent waves

__device__ __forceinline__ int reflect512(int i) {
    i = i < 0 ? -i : i;
    return i > 511 ? 1022 - i : i;
}
__device__ __forceinline__ float shfl_f(float v, int abyte) {
    return __int_as_float(__builtin_amdgcn_ds_bpermute(abyte, __float_as_int(v)));
}
__device__ __forceinline__ int shfl_i(int v, int abyte) {
    return __builtin_amdgcn_ds_bpermute(abyte, v);
}

__global__ __launch_bounds__(256)
void k_canny(const float* __restrict__ pred, const float* __restrict__ sketch,
             const float* __restrict__ matte, float* __restrict__ partials)
{
    const int lane = threadIdx.x & 63;
    const int wid  = threadIdx.x >> 6;
    const int tile = blockIdx.x * 4 + wid;
    const int tx = tile % XT;
    const int t2 = tile / XT;
    const int ty = t2 % YT;
    const int b  = t2 / YT;

    const int x  = tx*54 - 5 + lane;       // [-5, 544]
    const int xr = reflect512(x);
    const int y0 = ty*16;

    const float* p0 = pred + (size_t)b*3*HW_ + xr;
    const float* p1 = p0 + HW_;
    const float* p2 = p0 + 2*HW_;
    const float* mp = matte  + (size_t)b*HW_ + xr;
    const float* sp = sketch + (size_t)b*HW_ + xr;

    // bpermute byte addresses (pull from lane +/- k)
    const int am1 = ((lane-1)&63)<<2, ap1 = ((lane+1)&63)<<2;
    const int am2 = ((lane-2)&63)<<2, ap2 = ((lane+2)&63)<<2;

    const bool xin  = (x >= 0) & (x < 512);
    const bool xgt0 = (x > 0), xlt511 = (x < 511);
    const bool lv   = (lane >= 5) & (lane <= 58) & (x < 512);

    // register FIFOs (software pipeline, depth 15)
    float g_prev = 0.f;                       // gray row (prev step)
    float t0=0,t1=0,t2f=0,t3=0,t4=0;          // h-blur rows
    float bf0=0,bf1=0,bf2=0;                  // blur rows
    float mf0=0,mf1=0,mf2=0;                  // mag^2 rows
    int   ox0=0,oy0=0,ox1=0,oy1=0;            // NMS offsets (2-deep)
    int   e0=0,e1=0,e2=0;                     // class rows
    float skA=0,mtA=0,skB=0,mtB=0;            // loss operands (2-deep)
    float lacc = 0.f;

    for (int s = 0; s < 31; ++s) {
        // 1) gray load, row yL = y0-5+s (reflected); rows y0-5 .. y0+20
        float vg = 0.f;
        if (s <= 25) {
            int o = reflect512(y0 - 5 + s) * W_;
            vg = (p0[o] + p1[o] + p2[o]) * mp[o] * (1.f/3.f);
        }
        // loss prefetch for row yH(s+2) = y0-13+s
        float nsk = 0.f, nmt = 0.f;
        {
            int yS = y0 - 13 + s;
            if (yS >= y0 && yS < y0 + 16) { int o = yS*W_; nsk = sp[o]; nmt = mp[o]; }
        }
        // 2) horizontal gaussian for row y0-6+s (from g_prev, lane shuffles)
        float gm1 = shfl_f(g_prev, am1), gp1v = shfl_f(g_prev, ap1);
        float gm2 = shfl_f(g_prev, am2), gp2v = shfl_f(g_prev, ap2);
        float th = G0*(gm2+gp2v) + G1*(gm1+gp1v) + G2*g_prev;
        // 3) vertical gaussian for row y0-9+s (t-FIFO; reflect handled at load)
        float bl = G0*(t0+t4) + G1*(t1+t3) + G2*t2f;
        // 4) sobel -> mag^2 + NMS offset for row yM = y0-11+s
        int yM = y0 - 11 + s;
        float b0e = (yM > 0)   ? bf0 : bf1;      // y replicate
        float b2e = (yM < 511) ? bf2 : bf1;
        float cs  = b0e + 2.f*bf1 + b2e;         // column sum
        float rdv = b2e - b0e;                   // row diff
        float csm = shfl_f(cs, am1),  csp = shfl_f(cs, ap1);
        float rdm = shfl_f(rdv, am1), rdp = shfl_f(rdv, ap1);
        csm = xgt0 ? csm : cs;   csp = xlt511 ? csp : cs;    // x replicate
        rdm = xgt0 ? rdm : rdv;  rdp = xlt511 ? rdp : rdv;
        float gx = csp - csm;
        float gy = rdm + 2.f*rdv + rdp;
        float m2n = fmaf(gx*gx + gy*gy, 0.015625f, 1e-6f);
        bool iny = (yM >= 0) & (yM < 512);
        m2n = (iny & xin) ? m2n : 0.f;           // zero outside image (NMS pad)
        float agx = fabsf(gx), agy = fabsf(gy);
        int oxn, oyn;
        if      (agy <= 0.41421356f*agx) { oxn = (gx >= 0.f) ? 1 : -1; oyn = 0; }
        else if (agy >= 2.41421356f*agx) { oxn = 0; oyn = (gy > 0.f) ? -1 : 1; }
        else { oxn = (gx > 0.f) ? 1 : -1; oyn = (gy > 0.f) ? -1 : 1; }
        // 5) NMS + double threshold for row yE = y0-13+s (mag FIFO + delayed off)
        float m0m = shfl_f(mf0, am1), m0p = shfl_f(mf0, ap1);
        float m1m = shfl_f(mf1, am1), m1p = shfl_f(mf1, ap1);
        float m2m = shfl_f(mf2, am1), m2p = shfl_f(mf2, ap1);
        float r0v = (ox0 < 0) ? m0m : ((ox0 > 0) ? m0p : mf0);
        float r1v = (ox0 < 0) ? m1m : ((ox0 > 0) ? m1p : mf1);
        float r2v = (ox0 < 0) ? m2m : ((ox0 > 0) ? m2p : mf2);
        float n1  = (oy0 < 0) ? r0v : ((oy0 > 0) ? r2v : r1v);
        float r0w = (ox0 > 0) ? m0m : ((ox0 < 0) ? m0p : mf0);
        float r1w = (ox0 > 0) ? m1m : ((ox0 < 0) ? m1p : mf1);
        float r2w = (ox0 > 0) ? m2m : ((ox0 < 0) ? m2p : mf2);
        float n2  = (oy0 > 0) ? r0w : ((oy0 < 0) ? r2w : r1w);
        float mc = mf1;
        int cls = 0;
        if (mc > n1 && mc > n2) cls = (mc > 0.01f) + (mc > 0.04f);
        // 6) hysteresis + MSE for output row yH = y0-15+s
        if (s >= 15) {
            int e0m = shfl_i(e0, am1), e0p = shfl_i(e0, ap1);
            int e1m = shfl_i(e1, am1), e1p = shfl_i(e1, ap1);
            int e2m = shfl_i(e2, am1), e2p = shfl_i(e2, ap1);
            int orall = e0m|e0|e0p|e1m|e1p|e2m|e2|e2p;   // strong <=> bit1 set
            int fin = ((e1 == 1) && (orall & 2)) ? 2 : e1;
            float vf = 0.5f * (float)fin;
            float tt = fminf(fmaxf(skA*mtA, 0.f), 1.f);
            float d  = vf - tt;
            lacc += lv ? d*d : 0.f;
        }
        // FIFO shifts
        g_prev = vg;
        t0=t1; t1=t2f; t2f=t3; t3=t4; t4=th;
        bf0=bf1; bf1=bf2; bf2=bl;
        mf0=mf1; mf1=mf2; mf2=m2n;
        ox0=ox1; oy0=oy1; ox1=oxn; oy1=oyn;
        e0=e1; e1=e2; e2=cls;
        skA=skB; mtA=mtB; skB=nsk; mtB=nmt;
    }

    #pragma unroll
    for (int off = 32; off > 0; off >>= 1)
        lacc += __shfl_down(lacc, off, 64);
    if (lane == 0) partials[tile] = lacc;
}

__global__ __launch_bounds__(256)
void k_final(const float* __restrict__ partials, float* __restrict__ out) {
    int tid = threadIdx.x;
    float acc = 0.f;
    #pragma unroll
    for (int j = 0; j < NWAVE/256; ++j) acc += partials[j*256 + tid];
    #pragma unroll
    for (int off = 32; off > 0; off >>= 1)
        acc += __shfl_down(acc, off, 64);
    __shared__ float ws[4];
    if ((tid & 63) == 0) ws[tid >> 6] = acc;
    __syncthreads();
    if (tid == 0) out[0] = (ws[0] + ws[1] + ws[2] + ws[3]) * (1.0f / (float)N_);
}

extern "C" void kernel_launch(void* const* d_in, const int* in_sizes, int n_in,
                              void* d_out, int out_size, void* d_ws, size_t ws_size,
                              hipStream_t stream) {
    const float* pred   = (const float*)d_in[0];
    const float* sketch = (const float*)d_in[1];
    const float* matte  = (const float*)d_in[2];
    float* out = (float*)d_out;
    float* partials = (float*)d_ws;   // NWAVE floats

    k_canny<<<NBLKC, 256, 0, stream>>>(pred, sketch, matte, partials);
    k_final<<<1, 256, 0, stream>>>(partials, out);
}

// Round 14
// 35.589 us; speedup vs baseline: 1.7765x; 1.2256x over previous
//
#include <hip/hip_runtime.h>
#include <stdint.h>

#define B_  16
#define H_  512
#define W_  512
#define HW_ (H_*W_)
#define N_  (B_*HW_)

#define G0 0.054488685f
#define G1 0.244201342f
#define G2 0.402619947f

#define XT 10              // x tiles, 54 valid cols each (lane 5..58)
#define YT 32              // y tiles, 16 rows each
#define NWAVE (XT*YT*B_)   // 5120
#define NBLKC (NWAVE/4)    // 1280 blocks x 4 independent waves

__device__ __forceinline__ int reflect512(int i) {
    i = i < 0 ? -i : i;
    return i > 511 ? 1022 - i : i;
}
__device__ __forceinline__ float shfl_f(float v, int abyte) {
    return __int_as_float(__builtin_amdgcn_ds_bpermute(abyte, __float_as_int(v)));
}
__device__ __forceinline__ int shfl_i(int v, int abyte) {
    return __builtin_amdgcn_ds_bpermute(abyte, v);
}

__global__ __launch_bounds__(256)
void k_canny(const float* __restrict__ pred, const float* __restrict__ sketch,
             const float* __restrict__ matte, float* __restrict__ partials)
{
    const int lane = threadIdx.x & 63;
    const int wid  = threadIdx.x >> 6;
    const int tile = blockIdx.x * 4 + wid;
    const int tx = tile % XT;
    const int t2 = tile / XT;
    const int ty = t2 % YT;
    const int b  = t2 / YT;

    const int x  = tx*54 - 5 + lane;       // [-5, 544]
    const int xr = reflect512(x);
    const int y0 = ty*16;

    const float* p0 = pred + (size_t)b*3*HW_ + xr;
    const float* p1 = p0 + HW_;
    const float* p2 = p0 + 2*HW_;
    const float* mp = matte  + (size_t)b*HW_ + xr;
    const float* sp = sketch + (size_t)b*HW_ + xr;

    // bpermute byte addresses (pull from lane +/- k)
    const int am1 = ((lane-1)&63)<<2, ap1 = ((lane+1)&63)<<2;
    const int am2 = ((lane-2)&63)<<2, ap2 = ((lane+2)&63)<<2;

    const bool xin  = (x >= 0) & (x < 512);
    const bool xgt0 = (x > 0), xlt511 = (x < 511);
    const bool lv   = (lane >= 5) & (lane <= 58) & (x < 512);

    // register FIFOs (renamed away by full unroll)
    float g_prev = 0.f;                       // gray row (prev step)
    float t0=0,t1=0,t2f=0,t3=0,t4=0;          // h-blur rows
    float bf0=0,bf1=0,bf2=0;                  // blur rows
    float mf0=0,mf1=0,mf2=0;                  // mag^2 rows
    int   ox0=0,oy0=0,ox1=0,oy1=0;            // NMS offsets (2-deep)
    int   epk=0;                              // packed class rows e0|e1<<8|e2<<16
    float skA=0,mtA=0,skB=0,mtB=0;            // loss operands (2-deep)
    float lacc = 0.f;

    #pragma unroll
    for (int s = 0; s < 31; ++s) {
        // 1) gray load, row yL = y0-5+s (reflected); rows y0-5 .. y0+20
        float vg = 0.f;
        if (s <= 25) {
            int o = reflect512(y0 - 5 + s) * W_;
            vg = (p0[o] + p1[o] + p2[o]) * mp[o] * (1.f/3.f);
        }
        // loss prefetch for row yH(s+2) = y0-13+s
        float nsk = 0.f, nmt = 0.f;
        if (s >= 13 && s <= 28) {
            int o = (y0 - 13 + s)*W_;
            nsk = sp[o]; nmt = mp[o];
        }
        // 2) horizontal gaussian for row y0-6+s (from g_prev, lane shuffles)
        float gm1 = shfl_f(g_prev, am1), gp1v = shfl_f(g_prev, ap1);
        float gm2 = shfl_f(g_prev, am2), gp2v = shfl_f(g_prev, ap2);
        float th = G0*(gm2+gp2v) + G1*(gm1+gp1v) + G2*g_prev;
        // 3) vertical gaussian for row y0-9+s (t-FIFO; reflect handled at load)
        float bl = G0*(t0+t4) + G1*(t1+t3) + G2*t2f;
        // 4) sobel -> mag^2 + NMS offset for row yM = y0-11+s
        int yM = y0 - 11 + s;
        float b0e = (yM > 0)   ? bf0 : bf1;      // y replicate
        float b2e = (yM < 511) ? bf2 : bf1;
        float cs  = b0e + 2.f*bf1 + b2e;         // column sum
        float rdv = b2e - b0e;                   // row diff
        float csm = shfl_f(cs, am1),  csp = shfl_f(cs, ap1);
        float rdm = shfl_f(rdv, am1), rdp = shfl_f(rdv, ap1);
        csm = xgt0 ? csm : cs;   csp = xlt511 ? csp : cs;    // x replicate
        rdm = xgt0 ? rdm : rdv;  rdp = xlt511 ? rdp : rdv;
        float gx = csp - csm;
        float gy = rdm + 2.f*rdv + rdp;
        float m2n = fmaf(gx*gx + gy*gy, 0.015625f, 1e-6f);
        bool iny = (yM >= 0) & (yM < 512);
        m2n = (iny & xin) ? m2n : 0.f;           // zero outside image (NMS pad)
        float agx = fabsf(gx), agy = fabsf(gy);
        int oxn, oyn;
        if      (agy <= 0.41421356f*agx) { oxn = (gx >= 0.f) ? 1 : -1; oyn = 0; }
        else if (agy >= 2.41421356f*agx) { oxn = 0; oyn = (gy > 0.f) ? -1 : 1; }
        else { oxn = (gx > 0.f) ? 1 : -1; oyn = (gy > 0.f) ? -1 : 1; }
        // 5) NMS + double threshold for row yE = y0-13+s (mag FIFO + delayed off)
        float m0m = shfl_f(mf0, am1), m0p = shfl_f(mf0, ap1);
        float m1m = shfl_f(mf1, am1), m1p = shfl_f(mf1, ap1);
        float m2m = shfl_f(mf2, am1), m2p = shfl_f(mf2, ap1);
        float r0v = (ox0 < 0) ? m0m : ((ox0 > 0) ? m0p : mf0);
        float r1v = (ox0 < 0) ? m1m : ((ox0 > 0) ? m1p : mf1);
        float r2v = (ox0 < 0) ? m2m : ((ox0 > 0) ? m2p : mf2);
        float n1  = (oy0 < 0) ? r0v : ((oy0 > 0) ? r2v : r1v);
        float r0w = (ox0 > 0) ? m0m : ((ox0 < 0) ? m0p : mf0);
        float r1w = (ox0 > 0) ? m1m : ((ox0 < 0) ? m1p : mf1);
        float r2w = (ox0 > 0) ? m2m : ((ox0 < 0) ? m2p : mf2);
        float n2  = (oy0 > 0) ? r0w : ((oy0 < 0) ? r2w : r1w);
        float mc = mf1;
        int cls = 0;
        if (mc > n1 && mc > n2) cls = (mc > 0.01f) + (mc > 0.04f);
        // 6) hysteresis + MSE for output row yH = y0-15+s (packed-class, 2 bpermutes)
        if (s >= 15) {
            int epm = shfl_i(epk, am1), epp = shfl_i(epk, ap1);
            int strong = ((epm | epp) & 0x00020202) | (epk & 0x00020002);
            int e1v = (epk >> 8) & 0xff;
            int fin = ((e1v == 1) && strong) ? 2 : e1v;
            float vf = 0.5f * (float)fin;
            float tt = fminf(fmaxf(skA*mtA, 0.f), 1.f);
            float d  = vf - tt;
            lacc += lv ? d*d : 0.f;
        }
        // FIFO shifts (renamed away by unroll)
        g_prev = vg;
        t0=t1; t1=t2f; t2f=t3; t3=t4; t4=th;
        bf0=bf1; bf1=bf2; bf2=bl;
        mf0=mf1; mf1=mf2; mf2=m2n;
        ox0=ox1; oy0=oy1; ox1=oxn; oy1=oyn;
        epk = (epk >> 8) | (cls << 16);
        skA=skB; mtA=mtB; skB=nsk; mtB=nmt;
    }

    #pragma unroll
    for (int off = 32; off > 0; off >>= 1)
        lacc += __shfl_down(lacc, off, 64);
    if (lane == 0) partials[tile] = lacc;
}

__global__ __launch_bounds__(256)
void k_final(const float* __restrict__ partials, float* __restrict__ out) {
    int tid = threadIdx.x;
    float acc = 0.f;
    #pragma unroll
    for (int j = 0; j < NWAVE/256; ++j) acc += partials[j*256 + tid];
    #pragma unroll
    for (int off = 32; off > 0; off >>= 1)
        acc += __shfl_down(acc, off, 64);
    __shared__ float ws[4];
    if ((tid & 63) == 0) ws[tid >> 6] = acc;
    __syncthreads();
    if (tid == 0) out[0] = (ws[0] + ws[1] + ws[2] + ws[3]) * (1.0f / (float)N_);
}

extern "C" void kernel_launch(void* const* d_in, const int* in_sizes, int n_in,
                              void* d_out, int out_size, void* d_ws, size_t ws_size,
                              hipStream_t stream) {
    const float* pred   = (const float*)d_in[0];
    const float* sketch = (const float*)d_in[1];
    const float* matte  = (const float*)d_in[2];
    float* out = (float*)d_out;
    float* partials = (float*)d_ws;   // NWAVE floats

    k_canny<<<NBLKC, 256, 0, stream>>>(pred, sketch, matte, partials);
    k_final<<<1, 256, 0, stream>>>(partials, out);
}

// Round 15
// 32.742 us; speedup vs baseline: 1.9310x; 1.0869x over previous
//
#include <hip/hip_runtime.h>
#include <stdint.h>

#define B_  16
#define H_  512
#define W_  512
#define HW_ (H_*W_)
#define N_  (B_*HW_)

#define G0 0.054488685f
#define G1 0.244201342f
#define G2 0.402619947f

#define XT 10              // x tiles, 54 valid cols each (lane 5..58)
#define YT 32              // y tiles, 16 rows each
#define NWAVE (XT*YT*B_)   // 5120
#define NBLKC (NWAVE/4)    // 1280 blocks x 4 independent waves

__device__ __forceinline__ int reflect512(int i) {
    i = i < 0 ? -i : i;
    return i > 511 ? 1022 - i : i;
}
__device__ __forceinline__ float shfl_f(float v, int abyte) {
    return __int_as_float(__builtin_amdgcn_ds_bpermute(abyte, __float_as_int(v)));
}
__device__ __forceinline__ int shfl_i(int v, int abyte) {
    return __builtin_amdgcn_ds_bpermute(abyte, v);
}

__global__ __launch_bounds__(256)
void k_canny(const float* __restrict__ pred, const float* __restrict__ sketch,
             const float* __restrict__ matte, float* __restrict__ partials)
{
    const int lane = threadIdx.x & 63;
    const int wid  = threadIdx.x >> 6;
    const int tile = blockIdx.x * 4 + wid;
    const int tx = tile % XT;
    const int t2 = tile / XT;
    const int ty = t2 % YT;
    const int b  = t2 / YT;

    const int x  = tx*54 - 5 + lane;       // [-5, 544]
    const int xr = reflect512(x);
    const int y0 = ty*16;

    const float* p0 = pred + (size_t)b*3*HW_ + xr;
    const float* p1 = p0 + HW_;
    const float* p2 = p0 + 2*HW_;
    const float* mp = matte  + (size_t)b*HW_ + xr;
    const float* sp = sketch + (size_t)b*HW_ + xr;

    // bpermute byte addresses (pull from lane +/- k)
    const int am1 = ((lane-1)&63)<<2, ap1 = ((lane+1)&63)<<2;
    const int am2 = ((lane-2)&63)<<2, ap2 = ((lane+2)&63)<<2;

    const bool xin  = (x >= 0) & (x < 512);
    const bool xgt0 = (x > 0), xlt511 = (x < 511);
    const bool lv   = (lane >= 5) & (lane <= 58) & (x < 512);

    // register FIFOs (renamed away by full unroll)
    float g_prev = 0.f;                       // gray row (prev step)
    float t0=0,t1=0,t2f=0,t3=0,t4=0;          // h-blur rows
    float bf0=0,bf1=0,bf2=0;                  // blur rows
    float mf0=0,mf1=0,mf2=0;                  // mag^2 rows (center)
    float mfm0=0,mfm1=0,mfm2=0;               // mag^2 rows shifted left  (x-1)
    float mfp0=0,mfp1=0,mfp2=0;               // mag^2 rows shifted right (x+1)
    int   ox0=0,oy0=0,ox1=0,oy1=0;            // NMS offsets (2-deep)
    int   epk=0;                              // packed class rows e0|e1<<8|e2<<16
    float skA=0,mtA=0,skB=0,mtB=0;            // loss operands (2-deep)
    float lacc = 0.f;

    #pragma unroll
    for (int s = 0; s < 31; ++s) {
        // 1) gray load, row yL = y0-5+s (reflected); rows y0-5 .. y0+20
        float vg = 0.f;
        if (s <= 25) {
            int o = reflect512(y0 - 5 + s) * W_;
            vg = (p0[o] + p1[o] + p2[o]) * mp[o] * (1.f/3.f);
        }
        // loss prefetch for row yH(s+2) = y0-13+s
        float nsk = 0.f, nmt = 0.f;
        if (s >= 13 && s <= 28) {
            int o = (y0 - 13 + s)*W_;
            nsk = sp[o]; nmt = mp[o];
        }
        // 2) horizontal gaussian for row y0-6+s (from g_prev, lane shuffles)
        float gm1 = shfl_f(g_prev, am1), gp1v = shfl_f(g_prev, ap1);
        float gm2 = shfl_f(g_prev, am2), gp2v = shfl_f(g_prev, ap2);
        float th = G0*(gm2+gp2v) + G1*(gm1+gp1v) + G2*g_prev;
        // 3) vertical gaussian for row y0-9+s (t-FIFO; reflect handled at load)
        float bl = G0*(t0+t4) + G1*(t1+t3) + G2*t2f;
        // 4) sobel -> mag^2 + NMS offset for row yM = y0-11+s, plus +-1 shuffles
        int yM = y0 - 11 + s;
        float b0e = (yM > 0)   ? bf0 : bf1;      // y replicate
        float b2e = (yM < 511) ? bf2 : bf1;
        float cs  = b0e + 2.f*bf1 + b2e;         // column sum
        float rdv = b2e - b0e;                   // row diff
        float csm = shfl_f(cs, am1),  csp = shfl_f(cs, ap1);
        float rdm = shfl_f(rdv, am1), rdp = shfl_f(rdv, ap1);
        csm = xgt0 ? csm : cs;   csp = xlt511 ? csp : cs;    // x replicate
        rdm = xgt0 ? rdm : rdv;  rdp = xlt511 ? rdp : rdv;
        float gx = csp - csm;
        float gy = rdm + 2.f*rdv + rdp;
        float m2n = fmaf(gx*gx + gy*gy, 0.015625f, 1e-6f);
        bool iny = (yM >= 0) & (yM < 512);
        m2n = (iny & xin) ? m2n : 0.f;           // zero outside image (NMS pad)
        float mneg = shfl_f(m2n, am1);           // row's x-1 values (production-time)
        float mpos = shfl_f(m2n, ap1);           // row's x+1 values
        float agx = fabsf(gx), agy = fabsf(gy);
        int oxn, oyn;
        if      (agy <= 0.41421356f*agx) { oxn = (gx >= 0.f) ? 1 : -1; oyn = 0; }
        else if (agy >= 2.41421356f*agx) { oxn = 0; oyn = (gy > 0.f) ? -1 : 1; }
        else { oxn = (gx > 0.f) ? 1 : -1; oyn = (gy > 0.f) ? -1 : 1; }
        // 5) NMS + double threshold for row yE = y0-13+s (all operands in regs)
        float r0v = (ox0 < 0) ? mfm0 : ((ox0 > 0) ? mfp0 : mf0);
        float r1v = (ox0 < 0) ? mfm1 : ((ox0 > 0) ? mfp1 : mf1);
        float r2v = (ox0 < 0) ? mfm2 : ((ox0 > 0) ? mfp2 : mf2);
        float n1  = (oy0 < 0) ? r0v : ((oy0 > 0) ? r2v : r1v);
        float r0w = (ox0 > 0) ? mfm0 : ((ox0 < 0) ? mfp0 : mf0);
        float r1w = (ox0 > 0) ? mfm1 : ((ox0 < 0) ? mfp1 : mf1);
        float r2w = (ox0 > 0) ? mfm2 : ((ox0 < 0) ? mfp2 : mf2);
        float n2  = (oy0 > 0) ? r0w : ((oy0 < 0) ? r2w : r1w);
        float mc = mf1;
        int cls = 0;
        if (mc > n1 && mc > n2) cls = (mc > 0.01f) + (mc > 0.04f);
        // 6) hysteresis + MSE for output row yH = y0-15+s (packed-class, 2 bpermutes)
        if (s >= 15) {
            int epm = shfl_i(epk, am1), epp = shfl_i(epk, ap1);
            int strong = ((epm | epp) & 0x00020202) | (epk & 0x00020002);
            int e1v = (epk >> 8) & 0xff;
            int fin = ((e1v == 1) && strong) ? 2 : e1v;
            float vf = 0.5f * (float)fin;
            float tt = fminf(fmaxf(skA*mtA, 0.f), 1.f);
            float d  = vf - tt;
            lacc += lv ? d*d : 0.f;
        }
        // FIFO shifts (renamed away by unroll)
        g_prev = vg;
        t0=t1; t1=t2f; t2f=t3; t3=t4; t4=th;
        bf0=bf1; bf1=bf2; bf2=bl;
        mf0=mf1;   mf1=mf2;   mf2=m2n;
        mfm0=mfm1; mfm1=mfm2; mfm2=mneg;
        mfp0=mfp1; mfp1=mfp2; mfp2=mpos;
        ox0=ox1; oy0=oy1; ox1=oxn; oy1=oyn;
        epk = (epk >> 8) | (cls << 16);
        skA=skB; mtA=mtB; skB=nsk; mtB=nmt;
    }

    #pragma unroll
    for (int off = 32; off > 0; off >>= 1)
        lacc += __shfl_down(lacc, off, 64);
    if (lane == 0) partials[tile] = lacc;
}

__global__ __launch_bounds__(256)
void k_final(const float* __restrict__ partials, float* __restrict__ out) {
    int tid = threadIdx.x;
    float acc = 0.f;
    const float4* p4 = (const float4*)partials;
    #pragma unroll
    for (int j = 0; j < NWAVE/1024; ++j) {          // 5 float4 per thread
        float4 v = p4[j*256 + tid];
        acc += (v.x + v.y) + (v.z + v.w);
    }
    #pragma unroll
    for (int off = 32; off > 0; off >>= 1)
        acc += __shfl_down(acc, off, 64);
    __shared__ float ws[4];
    if ((tid & 63) == 0) ws[tid >> 6] = acc;
    __syncthreads();
    if (tid == 0) out[0] = (ws[0] + ws[1] + ws[2] + ws[3]) * (1.0f / (float)N_);
}

extern "C" void kernel_launch(void* const* d_in, const int* in_sizes, int n_in,
                              void* d_out, int out_size, void* d_ws, size_t ws_size,
                              hipStream_t stream) {
    const float* pred   = (const float*)d_in[0];
    const float* sketch = (const float*)d_in[1];
    const float* matte  = (const float*)d_in[2];
    float* out = (float*)d_out;
    float* partials = (float*)d_ws;   // NWAVE floats

    k_canny<<<NBLKC, 256, 0, stream>>>(pred, sketch, matte, partials);
    k_final<<<1, 256, 0, stream>>>(partials, out);
}